// Round 10
// baseline (246.525 us; speedup 1.0000x reference)
//
#include <hip/hip_runtime.h>
#include <hip/hip_bf16.h>

typedef __bf16 bf16_t;
typedef __attribute__((ext_vector_type(8))) __bf16 bf16x8;
typedef __attribute__((ext_vector_type(4))) __bf16 bf16x4;
typedef __attribute__((ext_vector_type(4))) float f32x4;
typedef __attribute__((ext_vector_type(16))) float f32x16;

#define MFMA16(A,B,C) __builtin_amdgcn_mfma_f32_16x16x32_bf16((A),(B),(C),0,0,0)
#define MFMA32(A,B,C) __builtin_amdgcn_mfma_f32_32x32x16_bf16((A),(B),(C),0,0,0)

#define BATCH 2
#define SEQ 2048
#define DMODEL 1024
#define NHEAD 16
#define HDIM 64
#define MROWS (BATCH * SEQ)   // 4096

// async 16B global->LDS. Global addr may be per-lane; LDS dest is
// wave-uniform base + lane*16.
__device__ __forceinline__ void async16(const bf16_t* g, bf16_t* l) {
    __builtin_amdgcn_global_load_lds(
        (const __attribute__((address_space(1))) unsigned int*)g,
        (__attribute__((address_space(3))) unsigned int*)l, 16, 0, 0);
}

// swizzled fragment loads: physical chunk = logical chunk ^ f(row)
// rows of 32 elems (64B, 4 chunks): f(row) = (row>>1)&3
__device__ __forceinline__ bf16x8 ldsA32(const bf16_t* base, int row, int chunk) {
    return *(const bf16x8*)&base[row * 32 + ((chunk ^ ((row >> 1) & 3)) << 3)];
}

// pack two fp32 -> 2 bf16 in one u32 (RNE)
__device__ __forceinline__ unsigned pk(float a, float b) {
    union { unsigned u; bf16_t h[2]; } t;
    t.h[0] = (bf16_t)a;
    t.h[1] = (bf16_t)b;
    return t.u;
}

// v_permlane32_swap_b32 d, s : swaps upper 32 lanes of d with lower 32 lanes
// of s. swap(lo, hi) produces exactly the two B-fragment words the repack
// needs (lo' for key+0..7 view, hi' for key+8..15 view).
__device__ __forceinline__ void plane32_swap(unsigned& d, unsigned& s) {
    asm("v_permlane32_swap_b32 %0, %1" : "+v"(d), "+v"(s));
}

// softmax + C->B repack for one 32-key S^T subtile: pexp, rs partial
// accumulate, pack into 2 B-fragments (pf[0], pf[1]).
__device__ __forceinline__ void sm_pack(const f32x16& st, float* rsp, bf16x8* pf) {
    float pexp[16];
#pragma unroll
    for (int r = 0; r < 16; ++r)
        pexp[r] = __builtin_amdgcn_exp2f(st[r]);
    rsp[0] += pexp[0] + pexp[4] + pexp[8] + pexp[12];
    rsp[1] += pexp[1] + pexp[5] + pexp[9] + pexp[13];
    rsp[2] += pexp[2] + pexp[6] + pexp[10] + pexp[14];
    rsp[3] += pexp[3] + pexp[7] + pexp[11] + pexp[15];
#pragma unroll
    for (int s1 = 0; s1 < 2; ++s1) {
        unsigned lo01 = pk(pexp[8 * s1 + 0], pexp[8 * s1 + 1]);
        unsigned lo23 = pk(pexp[8 * s1 + 2], pexp[8 * s1 + 3]);
        unsigned hi01 = pk(pexp[8 * s1 + 4], pexp[8 * s1 + 5]);
        unsigned hi23 = pk(pexp[8 * s1 + 6], pexp[8 * s1 + 7]);
        plane32_swap(lo01, hi01);
        plane32_swap(lo23, hi23);
        union { bf16x8 v; unsigned u[4]; } outv;
        outv.u[0] = lo01;
        outv.u[1] = lo23;
        outv.u[2] = hi01;
        outv.u[3] = hi23;
        pf[s1] = outv.v;
    }
}

// ---------------------------------------------------------------------------
// Fused splits. Blocks 0..4095: x -> bf16. Blocks 4096..8191: weights (hi
// only) with head-reorder (z<3: row r'=h*64+d takes old 16*d+h; Wq scaled
// 0.125*log2e so attention can use exp2); z==3 (Wo): identity order.
// ---------------------------------------------------------------------------
__global__ void split_kernel(const float* __restrict__ x, const float* __restrict__ Wq,
                             const float* __restrict__ Wk, const float* __restrict__ Wv,
                             const float* __restrict__ Wo, bf16_t* __restrict__ xh,
                             bf16_t* __restrict__ wh) {
    int blk = blockIdx.x;
    if (blk < 4096) {
        int i = blk * 256 + threadIdx.x;
        f32x4 v = ((const f32x4*)x)[i];
        bf16x4 h;
#pragma unroll
        for (int c = 0; c < 4; ++c) h[c] = (bf16_t)v[c];
        ((bf16x4*)xh)[i] = h;
        return;
    }
    int e = blk - 4096;
    int z = e >> 10;
    int i = (e & 1023) * 256 + threadIdx.x;       // 0..262143 (WE/4)
    const float* src = (z == 0) ? Wq : (z == 1) ? Wk : (z == 2) ? Wv : Wo;
    const float scale = (z == 0) ? 0.125f * 1.44269504088896f : 1.0f;
    int row = i >> 8, col4 = i & 255;
    int r_src;
    if (z < 3) {
        int h = row >> 6, d = row & 63;
        r_src = 16 * d + h;
    } else {
        r_src = row;
    }
    f32x4 v = ((const f32x4*)src)[r_src * 256 + col4];
    bf16x4 h4;
#pragma unroll
    for (int c = 0; c < 4; ++c) h4[c] = (bf16_t)(v[c] * scale);
    ((bf16x4*)(wh + (size_t)z * DMODEL * DMODEL))[i] = h4;
}

// ---------------------------------------------------------------------------
// QKV GEMM C = A * B^T, single-product bf16, 16x16x32 MFMA. 128x128x32 tile,
// 4 waves, double-buffered, 1 barrier/it. 1D grid 768, XCD swizzle. z==2
// epilogue writes V^T [bh][d][n] directly.
// ---------------------------------------------------------------------------
__global__ __launch_bounds__(256)
void gemm_qkv_kernel(const bf16_t* __restrict__ Ah, const bf16_t* __restrict__ Bh0,
                     bf16_t* __restrict__ Coh0, bf16_t* __restrict__ Vt,
                     int M, int Nn, int Kk) {
    __shared__ __align__(16) bf16_t smem[2][8192];  // 32 KB: A[128x32] | B[128x32]

    const int id = blockIdx.x;
    const int xcd = id & 7;
    const int t = id >> 3;          // 0..95
    const int n0i = t & 7;
    const int u = t >> 3;           // 0..11
    const int z = u >> 2;
    const int m0g = u & 3;
    const int m0 = (m0g * 8 + xcd) * 128;
    const int n0 = n0i * 128;

    const bf16_t* Bh = Bh0 + (size_t)z * Nn * Kk;
    const int tid = threadIdx.x;
    const int wave = tid >> 6, lane = tid & 63, lq = lane >> 4, ln = lane & 15;
    const int wr = wave >> 1, wc = wave & 1;

    // staging: 16 issues (A:8, B:8), 4 per wave
    const bf16_t* g_ptr[4];
    int l_off[4];
#pragma unroll
    for (int q = 0; q < 4; ++q) {
        int e = wave * 4 + q;
        int a = e >> 3, uu = e & 7;
        int C = uu * 64 + lane;
        int r = C >> 2, p = C & 3;
        int c = p ^ ((r >> 1) & 3);           // inverse swizzle on global side
        g_ptr[q] = (a == 0 ? Ah + (size_t)(m0 + r) * Kk
                           : Bh + (size_t)(n0 + r) * Kk) + c * 8;
        l_off[q] = a * 4096 + uu * 512;
    }

    f32x4 acc[4][4] = {};

#pragma unroll
    for (int q = 0; q < 4; ++q)
        async16(g_ptr[q], &smem[0][l_off[q]]);

    const int NIT = Kk / 32;
    for (int j = 0; j < NIT; ++j) {
        __syncthreads();
        if (j + 1 < NIT) {
#pragma unroll
            for (int q = 0; q < 4; ++q)
                async16(g_ptr[q] + (j + 1) * 32, &smem[(j + 1) & 1][l_off[q]]);
        }
        const bf16_t* cur = smem[j & 1];

        bf16x8 ah[4], bh[4];
#pragma unroll
        for (int tt = 0; tt < 4; ++tt) {
            ah[tt] = ldsA32(cur, wr * 64 + tt * 16 + ln, lq);
            bh[tt] = ldsA32(cur + 4096, wc * 64 + tt * 16 + ln, lq);
        }
#pragma unroll
        for (int tm = 0; tm < 4; ++tm)
#pragma unroll
            for (int tn = 0; tn < 4; ++tn)
                acc[tm][tn] = MFMA16(ah[tm], bh[tn], acc[tm][tn]);
    }

    // epilogue. 16x16 C/D: col = lane&15, row = (lane>>4)*4 + reg
    if (z != 2) {
#pragma unroll
        for (int tm = 0; tm < 4; ++tm)
#pragma unroll
            for (int tn = 0; tn < 4; ++tn)
#pragma unroll
                for (int p = 0; p < 4; ++p) {
                    int gm = m0 + wr * 64 + tm * 16 + lq * 4 + p;
                    int gn = n0 + wc * 64 + tn * 16 + ln;
                    Coh0[(size_t)z * M * Nn + (size_t)gm * Nn + gn] =
                        (bf16_t)acc[tm][tn][p];
                }
    } else {
        // V^T: [bh][d][SEQ]; gm -> (b, n), gn -> (h, d); 4 consecutive n per frag
#pragma unroll
        for (int tm = 0; tm < 4; ++tm)
#pragma unroll
            for (int tn = 0; tn < 4; ++tn) {
                int gn = n0 + wc * 64 + tn * 16 + ln;
                int hh = gn >> 6, dd = gn & 63;
                int gm0 = m0 + wr * 64 + tm * 16 + lq * 4;
                int bb = gm0 >> 11, nn = gm0 & 2047;
                bf16x4 v4;
#pragma unroll
                for (int p = 0; p < 4; ++p) v4[p] = (bf16_t)acc[tm][tn][p];
                *(bf16x4*)&Vt[(((size_t)(bb * NHEAD + hh)) * HDIM + dd) * SEQ + nn] = v4;
            }
    }
}

// ---------------------------------------------------------------------------
// Out-proj GEMM: C = A * B^T, single-product bf16, 16x16x32 MFMA, fp32 out.
// 64x128x32 tile, 1D grid 512, XCD swizzle. Double-buffered, 1 barrier/iter.
// ---------------------------------------------------------------------------
__global__ __launch_bounds__(256)
void gemm_out_kernel(const bf16_t* __restrict__ Ah, const bf16_t* __restrict__ Bh,
                     float* __restrict__ Cf, int M, int Nn, int Kk) {
    __shared__ __align__(16) bf16_t smem[2][6144];  // 24 KB: A 64x32 | B 128x32

    const int id = blockIdx.x;
    const int xcd = id & 7;
    const int t = id >> 3;          // 0..63
    const int n0i = t & 7;
    const int m0g = t >> 3;         // 0..7
    const int m0 = (m0g * 8 + xcd) * 64;
    const int n0 = n0i * 128;

    const int tid = threadIdx.x;
    const int wave = tid >> 6, lane = tid & 63, lq = lane >> 4, ln = lane & 15;
    const int wr = wave >> 1, wc = wave & 1;

    // 12 issues (A:4, B:8), 3 per wave
    const bf16_t* g_ptr[3];
    int l_off[3];
#pragma unroll
    for (int q = 0; q < 3; ++q) {
        int e = wave * 3 + q;
        const bf16_t* arr;
        int u, rowbase, lb;
        if (e < 4) { arr = Ah; u = e;     rowbase = m0; lb = 0; }
        else       { arr = Bh; u = e - 4; rowbase = n0; lb = 2048; }
        int r = u * 16 + (lane >> 2), p = lane & 3;
        int c = p ^ ((r >> 1) & 3);
        g_ptr[q] = arr + (size_t)(rowbase + r) * Kk + c * 8;
        l_off[q] = lb + u * 512;
    }

    f32x4 acc[2][4] = {};

#pragma unroll
    for (int q = 0; q < 3; ++q)
        async16(g_ptr[q], &smem[0][l_off[q]]);

    const int NIT = Kk / 32;
    for (int j = 0; j < NIT; ++j) {
        __syncthreads();
        if (j + 1 < NIT) {
#pragma unroll
            for (int q = 0; q < 3; ++q)
                async16(g_ptr[q] + (j + 1) * 32, &smem[(j + 1) & 1][l_off[q]]);
        }
        const bf16_t* cur = smem[j & 1];

        bf16x8 ah[2], bh[4];
#pragma unroll
        for (int tt = 0; tt < 2; ++tt)
            ah[tt] = ldsA32(cur, wr * 32 + tt * 16 + ln, lq);
#pragma unroll
        for (int tt = 0; tt < 4; ++tt)
            bh[tt] = ldsA32(cur + 2048, wc * 64 + tt * 16 + ln, lq);
#pragma unroll
        for (int tm = 0; tm < 2; ++tm)
#pragma unroll
            for (int tn = 0; tn < 4; ++tn)
                acc[tm][tn] = MFMA16(ah[tm], bh[tn], acc[tm][tn]);
    }

#pragma unroll
    for (int tm = 0; tm < 2; ++tm)
#pragma unroll
        for (int tn = 0; tn < 4; ++tn)
#pragma unroll
            for (int p = 0; p < 4; ++p) {
                int gm = m0 + wr * 32 + tm * 16 + lq * 4 + p;
                int gn = n0 + wc * 64 + tn * 16 + ln;
                Cf[(size_t)gm * Nn + gn] = acc[tm][tn][p];
            }
}

// ---------------------------------------------------------------------------
// Flash attention v8: R9 structure (512 thr = 2 key-groups x 4 waves, 256
// q-rows/block, grid 256 = 1 block/CU) + ONE-TILE SOFTWARE PIPELINE:
// iter j computes {QK+softmax(tile j+1)} || {PV(tile j)} -- two independent
// streams, so PV MFMAs hide the exp2/pack latency and vice versa (R9 showed
// no pipe >40% busy; the serial chain per wave was the limiter). Triple-
// buffered LDS (2g x 3 x 16KB = 96KB, 1 block/CU), raw s_barrier + per-wave
// vmcnt(0) (each tile's DMA has a full body of slack), unroll-3 keeps %3
// buffer indices and pf rotation static. zacc kills per-iter zero-fills.
// ---------------------------------------------------------------------------
__global__ __launch_bounds__(512, 1)
void attn_kernel(const bf16_t* __restrict__ Qh, const bf16_t* __restrict__ Kh,
                 const bf16_t* __restrict__ Vt, bf16_t* __restrict__ Ch) {
    __shared__ __align__(16) bf16_t smem[2][3][8192];  // [group][buf][K 4096|V 4096]

    const int id = blockIdx.x;                 // 256 blocks
    const int bh = ((id >> 6) << 3) | (id & 7);
    const int qt = (id >> 3) & 7;
    const int b = bh >> 4, h = bh & 15;
    const int q0 = qt * 256;
    const int tid = threadIdx.x;
    const int g = tid >> 8;                    // key-group 0/1 (1024 keys each)
    const int wv = (tid >> 6) & 3;             // wave within group, 0..3
    const int lane = tid & 63;
    const int ln32 = lane & 31, hl = lane >> 5;

    // Q fragments, 2 sets: set qs covers q-rows q0 + wv*64 + qs*32 + ln32.
    bf16x8 qfh[2][4];
#pragma unroll
    for (int qs = 0; qs < 2; ++qs) {
        size_t qrow = ((size_t)(b * SEQ + q0 + wv * 64 + qs * 32 + ln32)) * DMODEL +
                      h * HDIM + hl * 8;
#pragma unroll
        for (int c = 0; c < 4; ++c)
            qfh[qs][c] = *(const bf16x8*)&Qh[qrow + c * 16];
    }

    // hoisted fragment-address terms (swizzle xor is kt/dt-independent).
    const int xrow = ln32 * 64;
    int xc[4];
#pragma unroll
    for (int c = 0; c < 4; ++c)
        xc[c] = (((2 * c + hl) ^ (ln32 & 7)) << 3) + xrow;

    // staging: per group 16 issues/tile (K:8 by waves 0-1, V:8 by waves 2-3),
    // 4 per wave. Both K and V tiles are [64 rows][64 el], 128B rows.
    bf16_t* gsm = &smem[g][0][0];
    const bf16_t* g_cur[4];
    int l_off[4];
    size_t g_step[4];
#pragma unroll
    for (int q = 0; q < 4; ++q) {
        int e = wv * 4 + q;
        int a = e >> 3, u = e & 7;
        int r = u * 8 + (lane >> 3), p = lane & 7;
        int c = p ^ (r & 7);                   // inverse swizzle on global side
        if (a == 0) {                          // K tile [64 keys][64 el]
            g_cur[q] = Kh + ((size_t)(b * SEQ + g * 1024 + r)) * DMODEL +
                       h * HDIM + c * 8;
            l_off[q] = u * 512;
            g_step[q] = (size_t)64 * DMODEL;
        } else {                               // V^T tile [64 d][64 keys]
            g_cur[q] = Vt + ((size_t)(bh * HDIM + r)) * SEQ + g * 1024 + c * 8;
            l_off[q] = 4096 + u * 512;
            g_step[q] = 64;
        }
    }

    f32x16 o[2][2];                            // [qs][dt]
#pragma unroll
    for (int qs = 0; qs < 2; ++qs)
#pragma unroll
        for (int dt = 0; dt < 2; ++dt)
#pragma unroll
            for (int r = 0; r < 16; ++r) o[qs][dt][r] = 0.0f;
    f32x16 zacc;                               // persistent zero C-operand
#pragma unroll
    for (int r = 0; r < 16; ++r) zacc[r] = 0.0f;
    float rsA[4] = {0.f, 0.f, 0.f, 0.f};
    float rsB[4] = {0.f, 0.f, 0.f, 0.f};

    // QK+softmax+pack of one 64-key tile (buffer base Kc) -> pfA/pfB[4]
    auto QKPACK = [&](const bf16_t* Kc, bf16x8* pfAo, bf16x8* pfBo) {
#pragma unroll
        for (int kt = 0; kt < 2; ++kt) {
            bf16x8 kh[4];
#pragma unroll
            for (int c = 0; c < 4; ++c)
                kh[c] = *(const bf16x8*)&Kc[kt * 2048 + xc[c]];
            __builtin_amdgcn_s_setprio(1);
            f32x16 s0 = MFMA32(kh[0], qfh[0][0], zacc);
            f32x16 s1 = MFMA32(kh[0], qfh[1][0], zacc);
#pragma unroll
            for (int c = 1; c < 4; ++c) s0 = MFMA32(kh[c], qfh[0][c], s0);
#pragma unroll
            for (int c = 1; c < 4; ++c) s1 = MFMA32(kh[c], qfh[1][c], s1);
            __builtin_amdgcn_s_setprio(0);
            sm_pack(s0, rsA, &pfAo[kt * 2]);
            sm_pack(s1, rsB, &pfBo[kt * 2]);
        }
    };
    // PV of one 64-key tile (buffer V base Vc) using pfA/pfB
    auto PV = [&](const bf16_t* Vc, const bf16x8* pfAi, const bf16x8* pfBi) {
        __builtin_amdgcn_s_setprio(1);
#pragma unroll
        for (int s = 0; s < 4; ++s) {
            bf16x8 va0 = *(const bf16x8*)&Vc[xc[s]];
            bf16x8 va1 = *(const bf16x8*)&Vc[2048 + xc[s]];
            o[0][0] = MFMA32(va0, pfAi[s], o[0][0]);
            o[0][1] = MFMA32(va1, pfAi[s], o[0][1]);
            o[1][0] = MFMA32(va0, pfBi[s], o[1][0]);
            o[1][1] = MFMA32(va1, pfBi[s], o[1][1]);
        }
        __builtin_amdgcn_s_setprio(0);
    };
    auto ISSUE = [&](int bufi) {               // stage next tile into buf bufi
#pragma unroll
        for (int q = 0; q < 4; ++q)
            async16(g_cur[q], gsm + bufi * 8192 + l_off[q]);
    };
    auto ADVANCE = [&]() {
#pragma unroll
        for (int q = 0; q < 4; ++q) g_cur[q] += g_step[q];
    };

    // prologue: issue t0 (buf0), t1 (buf1); wait own t0; QK(t0)
    ISSUE(0); ADVANCE();
    ISSUE(1); ADVANCE();                       // g_cur now at t2
    asm volatile("s_waitcnt vmcnt(4)" ::: "memory");
    __builtin_amdgcn_s_barrier();
    __builtin_amdgcn_sched_barrier(0);
    bf16x8 pfAc[4], pfBc[4];
    QKPACK(gsm + 0 * 8192, pfAc, pfBc);

    // 15 pipelined iters: j = tile being PV'd; QK of tile j+1.
#pragma unroll 3
    for (int j = 0; j < 15; ++j) {
        asm volatile("s_waitcnt vmcnt(0)" ::: "memory");   // own t(j+1) landed
        __builtin_amdgcn_s_barrier();                       // all waves past j-1
        __builtin_amdgcn_sched_barrier(0);
        // stage t(j+2) into buf (j+2)%3 (tail: re-stage t15, counts constant)
        ISSUE((j + 2) % 3);
        if (j + 2 < 15) ADVANCE();             // freeze at t15 for the tail
        bf16x8 pfAn[4], pfBn[4];
        QKPACK(gsm + ((j + 1) % 3) * 8192, pfAn, pfBn);
        PV(gsm + (j % 3) * 8192 + 4096, pfAc, pfBc);
#pragma unroll
        for (int i = 0; i < 4; ++i) { pfAc[i] = pfAn[i]; pfBc[i] = pfBn[i]; }
    }
    // final PV of t15 (buf 15%3 = 0); in-flight tail DMA writes buf 1 only.
    PV(gsm + 0 * 8192 + 4096, pfAc, pfBc);

    float rs[2];
    rs[0] = (rsA[0] + rsA[1]) + (rsA[2] + rsA[3]);
    rs[1] = (rsB[0] + rsB[1]) + (rsB[2] + rsB[3]);
#pragma unroll
    for (int qs = 0; qs < 2; ++qs)
        rs[qs] += __shfl_xor(rs[qs], 32);      // full group-sum per q-row

    // ---- combine the two groups' partials, per-dt phase (cbuf 32KB) ----
    __syncthreads();                                 // (A) drains vmcnt(0) too
    float* cbuf = (float*)smem;                      // 32 d x 256 q f32 (32KB)
    float* rbuf = cbuf + 8192;                       // 256 row sums @32KB
#pragma unroll
    for (int dt = 0; dt < 2; ++dt) {
        if (g == 1) {
#pragma unroll
            for (int qs = 0; qs < 2; ++qs)
#pragma unroll
                for (int r = 0; r < 16; ++r) {
                    int d = (r & 3) + 8 * (r >> 2) + 4 * hl;
                    cbuf[d * 256 + wv * 64 + qs * 32 + ln32] = o[qs][dt][r];
                }
            if (dt == 0 && hl == 0) {
                rbuf[wv * 64 + ln32] = rs[0];
                rbuf[wv * 64 + 32 + ln32] = rs[1];
            }
        }
        __syncthreads();
        if (g == 0) {
#pragma unroll
            for (int qs = 0; qs < 2; ++qs) {
#pragma unroll
                for (int r = 0; r < 16; ++r) {
                    int d = (r & 3) + 8 * (r >> 2) + 4 * hl;
                    o[qs][dt][r] += cbuf[d * 256 + wv * 64 + qs * 32 + ln32];
                }
                if (dt == 0) rs[qs] += rbuf[wv * 64 + qs * 32 + ln32];
            }
        }
        __syncthreads();
    }
    float inv[2];
    inv[0] = (g == 0) ? 1.0f / rs[0] : 0.0f;
    inv[1] = (g == 0) ? 1.0f / rs[1] : 0.0f;

    // ---- normalize + transpose-write, per-dh phase (fbuf 256x33 f32) ----
    float* fbuf = (float*)smem;
#pragma unroll
    for (int dh = 0; dh < 2; ++dh) {
        if (g == 0) {
#pragma unroll
            for (int qs = 0; qs < 2; ++qs)
#pragma unroll
                for (int r = 0; r < 16; ++r) {
                    int d_loc = (r & 3) + 8 * (r >> 2) + 4 * hl;
                    fbuf[(wv * 64 + qs * 32 + ln32) * 33 + d_loc] =
                        o[qs][dh][r] * inv[qs];
                }
        }
        __syncthreads();
        // all 8 waves write: wave gw owns q-rows gw*32..gw*32+31
        {
            int gw = tid >> 6;                       // 0..7
#pragma unroll
            for (int qq = 0; qq < 16; ++qq) {
                int qrow = gw * 32 + hl * 16 + qq;
                float v = fbuf[qrow * 33 + ln32];
                size_t gidx = ((size_t)(b * SEQ + q0 + qrow)) * DMODEL +
                              h * HDIM + dh * 32 + ln32;
                Ch[gidx] = (bf16_t)v;
            }
        }
        __syncthreads();
    }
}

// ---------------------------------------------------------------------------
extern "C" void kernel_launch(void* const* d_in, const int* in_sizes, int n_in,
                              void* d_out, int out_size, void* d_ws, size_t ws_size,
                              hipStream_t stream) {
    const float* x  = (const float*)d_in[0];
    const float* Wq = (const float*)d_in[1];
    const float* Wk = (const float*)d_in[2];
    const float* Wv = (const float*)d_in[3];
    const float* Wo = (const float*)d_in[4];
    float* out = (float*)d_out;

    char* ws = (char*)d_ws;
    size_t off = 0;
    auto alloc = [&](size_t bytes) -> bf16_t* {
        bf16_t* p = (bf16_t*)(ws + off);
        off += (bytes + 255) & ~(size_t)255;
        return p;
    };
    const size_t XE = (size_t)MROWS * DMODEL;      // 4,194,304
    const size_t WE = (size_t)DMODEL * DMODEL;     // 1,048,576

    bf16_t* xh  = alloc(XE * 2);
    bf16_t* wh  = alloc(4 * WE * 2);   // q,k,v,o (q/k/v row-reordered, q scaled)
    bf16_t* qnh = alloc(3 * XE * 2);   // Q,K in concat layout (z==2 slab unused)
    bf16_t* vth = alloc(XE * 2);       // V^T per head (written by QKV epilogue)
    bf16_t* ch  = alloc(XE * 2);       // attn output
    (void)ws_size; (void)in_sizes; (void)n_in; (void)out_size;

    // 1. fused splits (hi only)
    split_kernel<<<8192, 256, 0, stream>>>(x, Wq, Wk, Wv, Wo, xh, wh);

    // 2. QKV projections (MFMA16) + fused V-transpose epilogue
    gemm_qkv_kernel<<<768, 256, 0, stream>>>(xh, wh, qnh, vth, MROWS, DMODEL, DMODEL);

    // 3. flash attention (pipelined QK(j+1) || PV(j)), XCD-swizzled
    attn_kernel<<<256, 512, 0, stream>>>(qnh, qnh + XE, vth, ch);

    // 4. output projection (MFMA16, single-product) -> fp32 d_out
    gemm_out_kernel<<<512, 256, 0, stream>>>(ch, wh + 3 * WE, out, MROWS, DMODEL, DMODEL);
}

// Round 11
// 171.260 us; speedup vs baseline: 1.4395x; 1.4395x over previous
//
#include <hip/hip_runtime.h>
#include <hip/hip_bf16.h>

typedef __bf16 bf16_t;
typedef __attribute__((ext_vector_type(8))) __bf16 bf16x8;
typedef __attribute__((ext_vector_type(4))) __bf16 bf16x4;
typedef __attribute__((ext_vector_type(4))) float f32x4;
typedef __attribute__((ext_vector_type(16))) float f32x16;

#define MFMA16(A,B,C) __builtin_amdgcn_mfma_f32_16x16x32_bf16((A),(B),(C),0,0,0)
#define MFMA32(A,B,C) __builtin_amdgcn_mfma_f32_32x32x16_bf16((A),(B),(C),0,0,0)

#define BATCH 2
#define SEQ 2048
#define DMODEL 1024
#define NHEAD 16
#define HDIM 64
#define MROWS (BATCH * SEQ)   // 4096

// async 16B global->LDS. Global addr may be per-lane; LDS dest is
// wave-uniform base + lane*16.
__device__ __forceinline__ void async16(const bf16_t* g, bf16_t* l) {
    __builtin_amdgcn_global_load_lds(
        (const __attribute__((address_space(1))) unsigned int*)g,
        (__attribute__((address_space(3))) unsigned int*)l, 16, 0, 0);
}

// swizzled fragment loads: physical chunk = logical chunk ^ f(row)
// rows of 32 elems (64B, 4 chunks): f(row) = (row>>1)&3
__device__ __forceinline__ bf16x8 ldsA32(const bf16_t* base, int row, int chunk) {
    return *(const bf16x8*)&base[row * 32 + ((chunk ^ ((row >> 1) & 3)) << 3)];
}

// pack two fp32 -> 2 bf16 in one u32 (RNE)
__device__ __forceinline__ unsigned pk(float a, float b) {
    union { unsigned u; bf16_t h[2]; } t;
    t.h[0] = (bf16_t)a;
    t.h[1] = (bf16_t)b;
    return t.u;
}

// v_permlane32_swap_b32 d, s : swaps upper 32 lanes of d with lower 32 lanes
// of s. swap(lo, hi) produces exactly the two B-fragment words the repack
// needs (lo' for key+0..7 view, hi' for key+8..15 view).
__device__ __forceinline__ void plane32_swap(unsigned& d, unsigned& s) {
    asm("v_permlane32_swap_b32 %0, %1" : "+v"(d), "+v"(s));
}

// softmax + C->B repack for one 32-key S^T subtile: pexp, rs partial
// accumulate, pack into 2 B-fragments (pf[0], pf[1]).
__device__ __forceinline__ void sm_pack(const f32x16& st, float* rsp, bf16x8* pf) {
    float pexp[16];
#pragma unroll
    for (int r = 0; r < 16; ++r)
        pexp[r] = __builtin_amdgcn_exp2f(st[r]);
    rsp[0] += pexp[0] + pexp[4] + pexp[8] + pexp[12];
    rsp[1] += pexp[1] + pexp[5] + pexp[9] + pexp[13];
    rsp[2] += pexp[2] + pexp[6] + pexp[10] + pexp[14];
    rsp[3] += pexp[3] + pexp[7] + pexp[11] + pexp[15];
#pragma unroll
    for (int s1 = 0; s1 < 2; ++s1) {
        unsigned lo01 = pk(pexp[8 * s1 + 0], pexp[8 * s1 + 1]);
        unsigned lo23 = pk(pexp[8 * s1 + 2], pexp[8 * s1 + 3]);
        unsigned hi01 = pk(pexp[8 * s1 + 4], pexp[8 * s1 + 5]);
        unsigned hi23 = pk(pexp[8 * s1 + 6], pexp[8 * s1 + 7]);
        plane32_swap(lo01, hi01);
        plane32_swap(lo23, hi23);
        union { bf16x8 v; unsigned u[4]; } outv;
        outv.u[0] = lo01;
        outv.u[1] = lo23;
        outv.u[2] = hi01;
        outv.u[3] = hi23;
        pf[s1] = outv.v;
    }
}

// ---------------------------------------------------------------------------
// Fused splits. Blocks 0..4095: x -> bf16. Blocks 4096..8191: weights (hi
// only) with head-reorder (z<3: row r'=h*64+d takes old 16*d+h; Wq scaled
// 0.125*log2e so attention can use exp2); z==3 (Wo): identity order.
// ---------------------------------------------------------------------------
__global__ void split_kernel(const float* __restrict__ x, const float* __restrict__ Wq,
                             const float* __restrict__ Wk, const float* __restrict__ Wv,
                             const float* __restrict__ Wo, bf16_t* __restrict__ xh,
                             bf16_t* __restrict__ wh) {
    int blk = blockIdx.x;
    if (blk < 4096) {
        int i = blk * 256 + threadIdx.x;
        f32x4 v = ((const f32x4*)x)[i];
        bf16x4 h;
#pragma unroll
        for (int c = 0; c < 4; ++c) h[c] = (bf16_t)v[c];
        ((bf16x4*)xh)[i] = h;
        return;
    }
    int e = blk - 4096;
    int z = e >> 10;
    int i = (e & 1023) * 256 + threadIdx.x;       // 0..262143 (WE/4)
    const float* src = (z == 0) ? Wq : (z == 1) ? Wk : (z == 2) ? Wv : Wo;
    const float scale = (z == 0) ? 0.125f * 1.44269504088896f : 1.0f;
    int row = i >> 8, col4 = i & 255;
    int r_src;
    if (z < 3) {
        int h = row >> 6, d = row & 63;
        r_src = 16 * d + h;
    } else {
        r_src = row;
    }
    f32x4 v = ((const f32x4*)src)[r_src * 256 + col4];
    bf16x4 h4;
#pragma unroll
    for (int c = 0; c < 4; ++c) h4[c] = (bf16_t)(v[c] * scale);
    ((bf16x4*)(wh + (size_t)z * DMODEL * DMODEL))[i] = h4;
}

// ---------------------------------------------------------------------------
// QKV GEMM C = A * B^T, single-product bf16, 16x16x32 MFMA. 128x128x32 tile,
// 4 waves, double-buffered, 1 barrier/it. 1D grid 768, XCD swizzle. z==2
// epilogue writes V^T [bh][d][n] directly.
// ---------------------------------------------------------------------------
__global__ __launch_bounds__(256)
void gemm_qkv_kernel(const bf16_t* __restrict__ Ah, const bf16_t* __restrict__ Bh0,
                     bf16_t* __restrict__ Coh0, bf16_t* __restrict__ Vt,
                     int M, int Nn, int Kk) {
    __shared__ __align__(16) bf16_t smem[2][8192];  // 32 KB: A[128x32] | B[128x32]

    const int id = blockIdx.x;
    const int xcd = id & 7;
    const int t = id >> 3;          // 0..95
    const int n0i = t & 7;
    const int u = t >> 3;           // 0..11
    const int z = u >> 2;
    const int m0g = u & 3;
    const int m0 = (m0g * 8 + xcd) * 128;
    const int n0 = n0i * 128;

    const bf16_t* Bh = Bh0 + (size_t)z * Nn * Kk;
    const int tid = threadIdx.x;
    const int wave = tid >> 6, lane = tid & 63, lq = lane >> 4, ln = lane & 15;
    const int wr = wave >> 1, wc = wave & 1;

    // staging: 16 issues (A:8, B:8), 4 per wave
    const bf16_t* g_ptr[4];
    int l_off[4];
#pragma unroll
    for (int q = 0; q < 4; ++q) {
        int e = wave * 4 + q;
        int a = e >> 3, uu = e & 7;
        int C = uu * 64 + lane;
        int r = C >> 2, p = C & 3;
        int c = p ^ ((r >> 1) & 3);           // inverse swizzle on global side
        g_ptr[q] = (a == 0 ? Ah + (size_t)(m0 + r) * Kk
                           : Bh + (size_t)(n0 + r) * Kk) + c * 8;
        l_off[q] = a * 4096 + uu * 512;
    }

    f32x4 acc[4][4] = {};

#pragma unroll
    for (int q = 0; q < 4; ++q)
        async16(g_ptr[q], &smem[0][l_off[q]]);

    const int NIT = Kk / 32;
    for (int j = 0; j < NIT; ++j) {
        __syncthreads();
        if (j + 1 < NIT) {
#pragma unroll
            for (int q = 0; q < 4; ++q)
                async16(g_ptr[q] + (j + 1) * 32, &smem[(j + 1) & 1][l_off[q]]);
        }
        const bf16_t* cur = smem[j & 1];

        bf16x8 ah[4], bh[4];
#pragma unroll
        for (int tt = 0; tt < 4; ++tt) {
            ah[tt] = ldsA32(cur, wr * 64 + tt * 16 + ln, lq);
            bh[tt] = ldsA32(cur + 4096, wc * 64 + tt * 16 + ln, lq);
        }
#pragma unroll
        for (int tm = 0; tm < 4; ++tm)
#pragma unroll
            for (int tn = 0; tn < 4; ++tn)
                acc[tm][tn] = MFMA16(ah[tm], bh[tn], acc[tm][tn]);
    }

    // epilogue. 16x16 C/D: col = lane&15, row = (lane>>4)*4 + reg
    if (z != 2) {
#pragma unroll
        for (int tm = 0; tm < 4; ++tm)
#pragma unroll
            for (int tn = 0; tn < 4; ++tn)
#pragma unroll
                for (int p = 0; p < 4; ++p) {
                    int gm = m0 + wr * 64 + tm * 16 + lq * 4 + p;
                    int gn = n0 + wc * 64 + tn * 16 + ln;
                    Coh0[(size_t)z * M * Nn + (size_t)gm * Nn + gn] =
                        (bf16_t)acc[tm][tn][p];
                }
    } else {
        // V^T: [bh][d][SEQ]; gm -> (b, n), gn -> (h, d); 4 consecutive n per frag
#pragma unroll
        for (int tm = 0; tm < 4; ++tm)
#pragma unroll
            for (int tn = 0; tn < 4; ++tn) {
                int gn = n0 + wc * 64 + tn * 16 + ln;
                int hh = gn >> 6, dd = gn & 63;
                int gm0 = m0 + wr * 64 + tm * 16 + lq * 4;
                int bb = gm0 >> 11, nn = gm0 & 2047;
                bf16x4 v4;
#pragma unroll
                for (int p = 0; p < 4; ++p) v4[p] = (bf16_t)acc[tm][tn][p];
                *(bf16x4*)&Vt[(((size_t)(bb * NHEAD + hh)) * HDIM + dd) * SEQ + nn] = v4;
            }
    }
}

// ---------------------------------------------------------------------------
// Out-proj GEMM: C = A * B^T, single-product bf16, 16x16x32 MFMA, fp32 out.
// 64x128x32 tile, 1D grid 512, XCD swizzle. Double-buffered, 1 barrier/iter.
// ---------------------------------------------------------------------------
__global__ __launch_bounds__(256)
void gemm_out_kernel(const bf16_t* __restrict__ Ah, const bf16_t* __restrict__ Bh,
                     float* __restrict__ Cf, int M, int Nn, int Kk) {
    __shared__ __align__(16) bf16_t smem[2][6144];  // 24 KB: A 64x32 | B 128x32

    const int id = blockIdx.x;
    const int xcd = id & 7;
    const int t = id >> 3;          // 0..63
    const int n0i = t & 7;
    const int m0g = t >> 3;         // 0..7
    const int m0 = (m0g * 8 + xcd) * 64;
    const int n0 = n0i * 128;

    const int tid = threadIdx.x;
    const int wave = tid >> 6, lane = tid & 63, lq = lane >> 4, ln = lane & 15;
    const int wr = wave >> 1, wc = wave & 1;

    // 12 issues (A:4, B:8), 3 per wave
    const bf16_t* g_ptr[3];
    int l_off[3];
#pragma unroll
    for (int q = 0; q < 3; ++q) {
        int e = wave * 3 + q;
        const bf16_t* arr;
        int u, rowbase, lb;
        if (e < 4) { arr = Ah; u = e;     rowbase = m0; lb = 0; }
        else       { arr = Bh; u = e - 4; rowbase = n0; lb = 2048; }
        int r = u * 16 + (lane >> 2), p = lane & 3;
        int c = p ^ ((r >> 1) & 3);
        g_ptr[q] = arr + (size_t)(rowbase + r) * Kk + c * 8;
        l_off[q] = lb + u * 512;
    }

    f32x4 acc[2][4] = {};

#pragma unroll
    for (int q = 0; q < 3; ++q)
        async16(g_ptr[q], &smem[0][l_off[q]]);

    const int NIT = Kk / 32;
    for (int j = 0; j < NIT; ++j) {
        __syncthreads();
        if (j + 1 < NIT) {
#pragma unroll
            for (int q = 0; q < 3; ++q)
                async16(g_ptr[q] + (j + 1) * 32, &smem[(j + 1) & 1][l_off[q]]);
        }
        const bf16_t* cur = smem[j & 1];

        bf16x8 ah[2], bh[4];
#pragma unroll
        for (int tt = 0; tt < 2; ++tt)
            ah[tt] = ldsA32(cur, wr * 32 + tt * 16 + ln, lq);
#pragma unroll
        for (int tt = 0; tt < 4; ++tt)
            bh[tt] = ldsA32(cur + 2048, wc * 64 + tt * 16 + ln, lq);
#pragma unroll
        for (int tm = 0; tm < 2; ++tm)
#pragma unroll
            for (int tn = 0; tn < 4; ++tn)
                acc[tm][tn] = MFMA16(ah[tm], bh[tn], acc[tm][tn]);
    }

#pragma unroll
    for (int tm = 0; tm < 2; ++tm)
#pragma unroll
        for (int tn = 0; tn < 4; ++tn)
#pragma unroll
            for (int p = 0; p < 4; ++p) {
                int gm = m0 + wr * 32 + tm * 16 + lq * 4 + p;
                int gn = n0 + wc * 64 + tn * 16 + ln;
                Cf[(size_t)gm * Nn + gn] = acc[tm][tn][p];
            }
}

// ---------------------------------------------------------------------------
// Flash attention v7b: exact R9 structure (512 thr = 2 key-groups x 4 waves,
// 256 q-rows/block, KVBLK=64 dbuf, grid 256 = 1 block/CU) + zacc: the QK
// S-subtile init goes through the first MFMA's C-operand (persistent zero
// registers) instead of 64 v_movs per iteration. R9 pipe accounting shows
// ~93% of SIMD issue slots consumed (VALU 40 + MFMA 26 + LDS 20 + TRANS 7):
// issue-bound, so instruction-count reduction is the only remaining lever.
// ---------------------------------------------------------------------------
__global__ __launch_bounds__(512, 1)
void attn_kernel(const bf16_t* __restrict__ Qh, const bf16_t* __restrict__ Kh,
                 const bf16_t* __restrict__ Vt, bf16_t* __restrict__ Ch) {
    __shared__ __align__(16) bf16_t smem[2][2][8192];  // [group][buf][K 4096|V 4096]

    const int id = blockIdx.x;                 // 256 blocks
    const int bh = ((id >> 6) << 3) | (id & 7);
    const int qt = (id >> 3) & 7;
    const int b = bh >> 4, h = bh & 15;
    const int q0 = qt * 256;
    const int tid = threadIdx.x;
    const int g = tid >> 8;                    // key-group 0/1 (1024 keys each)
    const int wv = (tid >> 6) & 3;             // wave within group, 0..3
    const int lane = tid & 63;
    const int ln32 = lane & 31, hl = lane >> 5;

    // Q fragments, 2 sets: set qs covers q-rows q0 + wv*64 + qs*32 + ln32.
    // B[q=ln32][k=hl*8+j], chained over hd.
    bf16x8 qfh[2][4];
#pragma unroll
    for (int qs = 0; qs < 2; ++qs) {
        size_t qrow = ((size_t)(b * SEQ + q0 + wv * 64 + qs * 32 + ln32)) * DMODEL +
                      h * HDIM + hl * 8;
#pragma unroll
        for (int c = 0; c < 4; ++c)
            qfh[qs][c] = *(const bf16x8*)&Qh[qrow + c * 16];
    }

    // hoisted fragment-address terms: rows kt*32+ln32 (K) and dt*32+ln32 (V)
    // have row&7 == ln32&7, so the swizzle xor is kt/dt-independent.
    const int xrow = ln32 * 64;
    int xc[4];
#pragma unroll
    for (int c = 0; c < 4; ++c)
        xc[c] = (((2 * c + hl) ^ (ln32 & 7)) << 3) + xrow;

    // staging: per group 16 issues/tile (K:8 by waves 0-1, V:8 by waves 2-3),
    // 4 per wave. Both K and V tiles are [64 rows][64 el], 128B rows.
    bf16_t* gsm = &smem[g][0][0];
    const bf16_t* g_cur[4];
    int l_off[4];
    size_t g_step[4];
#pragma unroll
    for (int q = 0; q < 4; ++q) {
        int e = wv * 4 + q;
        int a = e >> 3, u = e & 7;
        int r = u * 8 + (lane >> 3), p = lane & 7;
        int c = p ^ (r & 7);                   // inverse swizzle on global side
        if (a == 0) {                          // K tile [64 keys][64 el]
            g_cur[q] = Kh + ((size_t)(b * SEQ + g * 1024 + r)) * DMODEL +
                       h * HDIM + c * 8;
            l_off[q] = u * 512;
            g_step[q] = (size_t)64 * DMODEL;
        } else {                               // V^T tile [64 d][64 keys]
            g_cur[q] = Vt + ((size_t)(bh * HDIM + r)) * SEQ + g * 1024 + c * 8;
            l_off[q] = 4096 + u * 512;
            g_step[q] = 64;
        }
    }

    f32x16 o[2][2];                            // [qs][dt]
#pragma unroll
    for (int qs = 0; qs < 2; ++qs)
#pragma unroll
        for (int dt = 0; dt < 2; ++dt)
#pragma unroll
            for (int r = 0; r < 16; ++r) o[qs][dt][r] = 0.0f;
    f32x16 zacc;                               // persistent zero C-operand
#pragma unroll
    for (int r = 0; r < 16; ++r) zacc[r] = 0.0f;
    float rsA[4] = {0.f, 0.f, 0.f, 0.f};
    float rsB[4] = {0.f, 0.f, 0.f, 0.f};

    // prologue: tile 0 into buf 0
#pragma unroll
    for (int q = 0; q < 4; ++q) {
        async16(g_cur[q], gsm + l_off[q]);
        g_cur[q] += g_step[q];
    }

    for (int j = 0; j < 16; ++j) {
        __syncthreads();  // buf j&1 DMA landed; reads of buf (j+1)&1 done
        if (j < 15) {
#pragma unroll
            for (int q = 0; q < 4; ++q) {
                async16(g_cur[q], gsm + ((j + 1) & 1) * 8192 + l_off[q]);
                g_cur[q] += g_step[q];
            }
        }
        const bf16_t* Kc = gsm + (j & 1) * 8192;
        const bf16_t* Vc = Kc + 4096;

        bf16x8 pfA[4], pfB[4];
#pragma unroll
        for (int kt = 0; kt < 2; ++kt) {
            // K fragments read once, feed both q-sets.
            bf16x8 kh[4];
#pragma unroll
            for (int c = 0; c < 4; ++c)
                kh[c] = *(const bf16x8*)&Kc[kt * 2048 + xc[c]];
            // S^T subtile: D[key = kt*32 + (r&3)+8*(r>>2)+4*hl][q = ln32]
            __builtin_amdgcn_s_setprio(1);
            f32x16 s0 = MFMA32(kh[0], qfh[0][0], zacc);
            f32x16 s1 = MFMA32(kh[0], qfh[1][0], zacc);
#pragma unroll
            for (int c = 1; c < 4; ++c)
                s0 = MFMA32(kh[c], qfh[0][c], s0);
#pragma unroll
            for (int c = 1; c < 4; ++c)
                s1 = MFMA32(kh[c], qfh[1][c], s1);
            __builtin_amdgcn_s_setprio(0);
            sm_pack(s0, rsA, &pfA[kt * 2]);
            sm_pack(s1, rsB, &pfB[kt * 2]);
        }
        // O^T += V^T * P; V fragments read once, feed both q-sets.
        __builtin_amdgcn_s_setprio(1);
#pragma unroll
        for (int s = 0; s < 4; ++s) {
            bf16x8 va0 = *(const bf16x8*)&Vc[xc[s]];
            bf16x8 va1 = *(const bf16x8*)&Vc[2048 + xc[s]];
            o[0][0] = MFMA32(va0, pfA[s], o[0][0]);
            o[0][1] = MFMA32(va1, pfA[s], o[0][1]);
            o[1][0] = MFMA32(va0, pfB[s], o[1][0]);
            o[1][1] = MFMA32(va1, pfB[s], o[1][1]);
        }
        __builtin_amdgcn_s_setprio(0);
    }

    float rs[2];
    rs[0] = (rsA[0] + rsA[1]) + (rsA[2] + rsA[3]);
    rs[1] = (rsB[0] + rsB[1]) + (rsB[2] + rsB[3]);
#pragma unroll
    for (int qs = 0; qs < 2; ++qs)
        rs[qs] += __shfl_xor(rs[qs], 32);      // full group-sum per q-row

    // ---- combine the two groups' partials, per-dt phase (cbuf 32KB) ----
    __syncthreads();                                 // (A) j-loop reads done
    float* cbuf = (float*)smem;                      // 32 d x 256 q f32 (32KB)
    float* rbuf = cbuf + 8192;                       // 256 row sums @32KB
#pragma unroll
    for (int dt = 0; dt < 2; ++dt) {
        if (g == 1) {
#pragma unroll
            for (int qs = 0; qs < 2; ++qs)
#pragma unroll
                for (int r = 0; r < 16; ++r) {
                    int d = (r & 3) + 8 * (r >> 2) + 4 * hl;
                    cbuf[d * 256 + wv * 64 + qs * 32 + ln32] = o[qs][dt][r];
                }
            if (dt == 0 && hl == 0) {
                rbuf[wv * 64 + ln32] = rs[0];
                rbuf[wv * 64 + 32 + ln32] = rs[1];
            }
        }
        __syncthreads();
        if (g == 0) {
#pragma unroll
            for (int qs = 0; qs < 2; ++qs) {
#pragma unroll
                for (int r = 0; r < 16; ++r) {
                    int d = (r & 3) + 8 * (r >> 2) + 4 * hl;
                    o[qs][dt][r] += cbuf[d * 256 + wv * 64 + qs * 32 + ln32];
                }
                if (dt == 0) rs[qs] += rbuf[wv * 64 + qs * 32 + ln32];
            }
        }
        __syncthreads();
    }
    float inv[2];
    inv[0] = (g == 0) ? 1.0f / rs[0] : 0.0f;
    inv[1] = (g == 0) ? 1.0f / rs[1] : 0.0f;

    // ---- normalize + transpose-write, per-dh phase (fbuf 256x33 f32) ----
    float* fbuf = (float*)smem;
#pragma unroll
    for (int dh = 0; dh < 2; ++dh) {
        if (g == 0) {
#pragma unroll
            for (int qs = 0; qs < 2; ++qs)
#pragma unroll
                for (int r = 0; r < 16; ++r) {
                    int d_loc = (r & 3) + 8 * (r >> 2) + 4 * hl;
                    fbuf[(wv * 64 + qs * 32 + ln32) * 33 + d_loc] =
                        o[qs][dh][r] * inv[qs];
                }
        }
        __syncthreads();
        // all 8 waves write: wave gw owns q-rows gw*32..gw*32+31
        {
            int gw = tid >> 6;                       // 0..7
#pragma unroll
            for (int qq = 0; qq < 16; ++qq) {
                int qrow = gw * 32 + hl * 16 + qq;
                float v = fbuf[qrow * 33 + ln32];
                size_t gidx = ((size_t)(b * SEQ + q0 + qrow)) * DMODEL +
                              h * HDIM + dh * 32 + ln32;
                Ch[gidx] = (bf16_t)v;
            }
        }
        __syncthreads();
    }
}

// ---------------------------------------------------------------------------
extern "C" void kernel_launch(void* const* d_in, const int* in_sizes, int n_in,
                              void* d_out, int out_size, void* d_ws, size_t ws_size,
                              hipStream_t stream) {
    const float* x  = (const float*)d_in[0];
    const float* Wq = (const float*)d_in[1];
    const float* Wk = (const float*)d_in[2];
    const float* Wv = (const float*)d_in[3];
    const float* Wo = (const float*)d_in[4];
    float* out = (float*)d_out;

    char* ws = (char*)d_ws;
    size_t off = 0;
    auto alloc = [&](size_t bytes) -> bf16_t* {
        bf16_t* p = (bf16_t*)(ws + off);
        off += (bytes + 255) & ~(size_t)255;
        return p;
    };
    const size_t XE = (size_t)MROWS * DMODEL;      // 4,194,304
    const size_t WE = (size_t)DMODEL * DMODEL;     // 1,048,576

    bf16_t* xh  = alloc(XE * 2);
    bf16_t* wh  = alloc(4 * WE * 2);   // q,k,v,o (q/k/v row-reordered, q scaled)
    bf16_t* qnh = alloc(3 * XE * 2);   // Q,K in concat layout (z==2 slab unused)
    bf16_t* vth = alloc(XE * 2);       // V^T per head (written by QKV epilogue)
    bf16_t* ch  = alloc(XE * 2);       // attn output
    (void)ws_size; (void)in_sizes; (void)n_in; (void)out_size;

    // 1. fused splits (hi only)
    split_kernel<<<8192, 256, 0, stream>>>(x, Wq, Wk, Wv, Wo, xh, wh);

    // 2. QKV projections (MFMA16) + fused V-transpose epilogue
    gemm_qkv_kernel<<<768, 256, 0, stream>>>(xh, wh, qnh, vth, MROWS, DMODEL, DMODEL);

    // 3. flash attention (256 q-rows/block, 4-wave tile sharing), XCD-swizzled
    attn_kernel<<<256, 512, 0, stream>>>(qnh, qnh + XE, vth, ch);

    // 4. output projection (MFMA16, single-product) -> fp32 d_out
    gemm_out_kernel<<<512, 256, 0, stream>>>(ch, wh + 3 * WE, out, MROWS, DMODEL, DMODEL);
}